// Round 7
// baseline (529.969 us; speedup 1.0000x reference)
//
#include <hip/hip_runtime.h>

#define DH 64
#define BN_EPS 1e-5f

typedef float2 f2;

__device__ __forceinline__ float lane_bcast(float v, int k) {
  return __int_as_float(__builtin_amdgcn_readlane(__float_as_int(v), k));
}

__device__ __forceinline__ f2 row2(const float* __restrict__ hn, int r, int sl) {
  return ((const f2*)(hn + (size_t)r * DH))[sl];
}

__global__ __launch_bounds__(256) void k_count(const int* __restrict__ dst,
                                               int* __restrict__ degi, int e) {
  int i = blockIdx.x * 256 + threadIdx.x;
  if (i < e) atomicAdd(&degi[dst[i]], 1);
}

// Per-block scan: local exclusive prefix -> loc (=cursor buf), block total -> partial.
__global__ __launch_bounds__(256) void k_scan1(const int* __restrict__ degi,
    float* __restrict__ dinv, int* __restrict__ loc, int* __restrict__ partial, int n)
{
  const int t = threadIdx.x;
  const int i = blockIdx.x * 256 + t;
  int v = (i < n) ? degi[i] : 0;
  if (i < n) dinv[i] = 1.0f / sqrtf((float)v + 1.0f);
  __shared__ int sc[256];
  sc[t] = v;
  __syncthreads();
  #pragma unroll
  for (int d = 1; d < 256; d <<= 1) {
    int u = (t >= d) ? sc[t - d] : 0;
    __syncthreads();
    sc[t] += u;
    __syncthreads();
  }
  if (i < n) loc[i] = sc[t] - v;              // local exclusive
  if (t == 255) partial[blockIdx.x] = sc[t];  // block total
}

__global__ __launch_bounds__(256) void k_scan2(const int* __restrict__ partial,
    int* __restrict__ loc_cursor, int* __restrict__ off, int n, int e)
{
  const int t = threadIdx.x;
  __shared__ int red[256];
  int s = 0;
  for (int i = t; i < (int)blockIdx.x; i += 256) s += partial[i];
  red[t] = s;
  __syncthreads();
  #pragma unroll
  for (int d = 128; d; d >>= 1) {
    if (t < d) red[t] += red[t + d];
    __syncthreads();
  }
  const int base = red[0];
  const int i = blockIdx.x * 256 + t;
  if (i < n) {
    int o = loc_cursor[i] + base;
    off[i] = o;
    loc_cursor[i] = o;  // becomes the fill cursor
  }
  if (i == n) off[n] = e;
}

__global__ __launch_bounds__(256) void k_fill(const int* __restrict__ src,
    const int* __restrict__ dst, int* __restrict__ cursor,
    int* __restrict__ csr, int e)
{
  int i = blockIdx.x * 256 + threadIdx.x;
  if (i < e) {
    int p = atomicAdd(&cursor[dst[i]], 1);
    csr[p] = src[i];
  }
}

// hn[r][c] = (X@W)[r][c] * dinv[r].
// APPLY: X is previous layer's pre-BN y; BN scale/shift computed inline from
// stats S (sum, sumsq) + gamma/beta, then relu applied on load.
template<int K, bool APPLY>
__global__ __launch_bounds__(256) void k_gemm(const float* __restrict__ X,
    const float* __restrict__ W, const float* __restrict__ dinv,
    const float* __restrict__ S, const float* __restrict__ gamma,
    const float* __restrict__ beta, float inv_n, float* __restrict__ hn, int n)
{
  __shared__ float Wl[K * DH];
  for (int i = threadIdx.x; i < K * DH; i += 256) Wl[i] = W[i];
  __syncthreads();
  const int lane = threadIdx.x & 63;
  const int wid = blockIdx.x * 4 + (threadIdx.x >> 6);
  const int r0 = wid * 4;
  if (r0 >= n) return;
  float sc = 0.f, sh = 0.f;
  if (APPLY) {
    float mu = S[lane] * inv_n;
    float var = S[DH + lane] * inv_n - mu * mu;
    float scv = gamma[lane] / sqrtf(var + BN_EPS);
    sc = scv;
    sh = fmaf(-mu, scv, beta[lane]);
  }
  float xa[4], xb[4], acc[4];
  #pragma unroll
  for (int i = 0; i < 4; i++) {
    int r = r0 + i; if (r > n - 1) r = n - 1;
    const float* xr = X + (size_t)r * K;
    float v = xr[lane];
    if (APPLY) v = fmaxf(0.f, fmaf(v, sc, sh));
    xa[i] = v;
    if (K == 128) xb[i] = xr[DH + lane];
    acc[i] = 0.f;
  }
  #pragma unroll
  for (int k = 0; k < DH; k++) {
    float w = Wl[k * DH + lane];
    #pragma unroll
    for (int i = 0; i < 4; i++) acc[i] = fmaf(lane_bcast(xa[i], k), w, acc[i]);
  }
  if (K == 128) {
    #pragma unroll
    for (int k = 0; k < DH; k++) {
      float w = Wl[(DH + k) * DH + lane];
      #pragma unroll
      for (int i = 0; i < 4; i++) acc[i] = fmaf(lane_bcast(xb[i], k), w, acc[i]);
    }
  }
  #pragma unroll
  for (int i = 0; i < 4; i++) {
    if (r0 + i < n) hn[(size_t)(r0 + i) * DH + lane] = acc[i] * dinv[r0 + i];
  }
}

// Fused aggregate + BN-stats. Two levers for memory-level parallelism:
//  (1) paired-f2 gathers: lanes 0-31 (half 0) walk even-relative neighbor
//      indices, lanes 32-63 odd; each lane holds cols (2sl, 2sl+1) so one
//      load instruction covers TWO edges; halves combine via shfl_xor(32).
//  (2) two-row interleave: each wave processes rows dA and dB=dA+nw with
//      independent accumulator chains -> up to 16 edges in flight per wave.
__global__ __launch_bounds__(256) void k_aggbn(const float* __restrict__ hn,
    const int* __restrict__ off, const int* __restrict__ csr,
    const float* __restrict__ dinv, const float* __restrict__ b,
    float* __restrict__ y, float* __restrict__ S, int n)
{
  const int lane = threadIdx.x & 63;
  const int half = lane >> 5;
  const int sl = lane & 31;
  const int w = threadIdx.x >> 6;
  const int wid = __builtin_amdgcn_readfirstlane(blockIdx.x * 4 + w);
  const int nw = gridDim.x * 4;
  const f2 bias = ((const f2*)b)[sl];
  f2 s1 = {0.f, 0.f}, s2 = {0.f, 0.f};

  for (int dA = wid; dA < n; dA += 2 * nw) {
    const int dB = dA + nw;
    const bool hasB = (dB < n);
    f2 a0 = {0.f,0.f}, a1 = {0.f,0.f}, a2 = {0.f,0.f}, a3 = {0.f,0.f};
    f2 c0 = {0.f,0.f}, c1 = {0.f,0.f}, c2 = {0.f,0.f}, c3 = {0.f,0.f};
    if (half == 0) a0 = row2(hn, dA, sl);         // self-loop A
    int jA = off[dA] + half;
    const int eA = off[dA + 1];
    int jB = 0, eB = 0;
    if (hasB) {
      if (half == 0) c0 = row2(hn, dB, sl);       // self-loop B
      jB = off[dB] + half;
      eB = off[dB + 1];
    }
    // Interleaved main: 8 independent f2 gathers (16 edges) in flight.
    for (; jA + 6 < eA && jB + 6 < eB; jA += 8, jB += 8) {
      int iA0 = csr[jA], iA1 = csr[jA + 2], iA2 = csr[jA + 4], iA3 = csr[jA + 6];
      int iB0 = csr[jB], iB1 = csr[jB + 2], iB2 = csr[jB + 4], iB3 = csr[jB + 6];
      f2 g0 = row2(hn, iA0, sl);
      f2 g1 = row2(hn, iA1, sl);
      f2 g2 = row2(hn, iA2, sl);
      f2 g3 = row2(hn, iA3, sl);
      f2 h0 = row2(hn, iB0, sl);
      f2 h1 = row2(hn, iB1, sl);
      f2 h2 = row2(hn, iB2, sl);
      f2 h3 = row2(hn, iB3, sl);
      a0.x += g0.x; a0.y += g0.y;  a1.x += g1.x; a1.y += g1.y;
      a2.x += g2.x; a2.y += g2.y;  a3.x += g3.x; a3.y += g3.y;
      c0.x += h0.x; c0.y += h0.y;  c1.x += h1.x; c1.y += h1.y;
      c2.x += h2.x; c2.y += h2.y;  c3.x += h3.x; c3.y += h3.y;
    }
    // Drain A.
    for (; jA + 6 < eA; jA += 8) {
      int i0 = csr[jA], i1 = csr[jA + 2], i2 = csr[jA + 4], i3 = csr[jA + 6];
      f2 g0 = row2(hn, i0, sl);
      f2 g1 = row2(hn, i1, sl);
      f2 g2 = row2(hn, i2, sl);
      f2 g3 = row2(hn, i3, sl);
      a0.x += g0.x; a0.y += g0.y;  a1.x += g1.x; a1.y += g1.y;
      a2.x += g2.x; a2.y += g2.y;  a3.x += g3.x; a3.y += g3.y;
    }
    for (; jA < eA; jA += 2) {
      f2 g = row2(hn, csr[jA], sl);
      a0.x += g.x; a0.y += g.y;
    }
    // Drain B.
    if (hasB) {
      for (; jB + 6 < eB; jB += 8) {
        int i0 = csr[jB], i1 = csr[jB + 2], i2 = csr[jB + 4], i3 = csr[jB + 6];
        f2 h0 = row2(hn, i0, sl);
        f2 h1 = row2(hn, i1, sl);
        f2 h2 = row2(hn, i2, sl);
        f2 h3 = row2(hn, i3, sl);
        c0.x += h0.x; c0.y += h0.y;  c1.x += h1.x; c1.y += h1.y;
        c2.x += h2.x; c2.y += h2.y;  c3.x += h3.x; c3.y += h3.y;
      }
      for (; jB < eB; jB += 2) {
        f2 h = row2(hn, csr[jB], sl);
        c0.x += h.x; c0.y += h.y;
      }
    }
    // Finish A.
    {
      float tx = (a0.x + a1.x) + (a2.x + a3.x);
      float ty = (a0.y + a1.y) + (a2.y + a3.y);
      tx += __shfl_xor(tx, 32);
      ty += __shfl_xor(ty, 32);
      if (half == 0) {
        float di = dinv[dA];
        f2 v;
        v.x = fmaf(tx, di, bias.x);
        v.y = fmaf(ty, di, bias.y);
        ((f2*)(y + (size_t)dA * DH))[sl] = v;
        s1.x += v.x; s1.y += v.y;
        s2.x = fmaf(v.x, v.x, s2.x);
        s2.y = fmaf(v.y, v.y, s2.y);
      }
    }
    // Finish B.
    if (hasB) {
      float tx = (c0.x + c1.x) + (c2.x + c3.x);
      float ty = (c0.y + c1.y) + (c2.y + c3.y);
      tx += __shfl_xor(tx, 32);
      ty += __shfl_xor(ty, 32);
      if (half == 0) {
        float di = dinv[dB];
        f2 v;
        v.x = fmaf(tx, di, bias.x);
        v.y = fmaf(ty, di, bias.y);
        ((f2*)(y + (size_t)dB * DH))[sl] = v;
        s1.x += v.x; s1.y += v.y;
        s2.x = fmaf(v.x, v.x, s2.x);
        s2.y = fmaf(v.y, v.y, s2.y);
      }
    }
  }

  __shared__ float L[8][DH];
  if (half == 0) {  // half 1 holds no stats
    ((f2*)&L[w][0])[sl] = s1;
    ((f2*)&L[4 + w][0])[sl] = s2;
  }
  __syncthreads();
  if (threadIdx.x < DH) {
    float t1 = L[0][threadIdx.x] + L[1][threadIdx.x] + L[2][threadIdx.x] + L[3][threadIdx.x];
    float t2 = L[4][threadIdx.x] + L[5][threadIdx.x] + L[6][threadIdx.x] + L[7][threadIdx.x];
    atomicAdd(&S[threadIdx.x], t1);
    atomicAdd(&S[DH + threadIdx.x], t2);
  }
}

// out[r] = sum_c relu(BN(y[r][c])) * Wout[c] + bout  (BN inline from S)
__global__ __launch_bounds__(256) void k_out(const float* __restrict__ y,
    const float* __restrict__ S, const float* __restrict__ gamma,
    const float* __restrict__ beta, float inv_n,
    const float* __restrict__ Wout, const float* __restrict__ bout,
    float* __restrict__ out, int n)
{
  const int lane = threadIdx.x & 63;
  const int wid = blockIdx.x * 4 + (threadIdx.x >> 6);
  const int nw = gridDim.x * 4;
  float mu = S[lane] * inv_n;
  float var = S[DH + lane] * inv_n - mu * mu;
  float scv = gamma[lane] / sqrtf(var + BN_EPS);
  float sc = scv;
  float sh = fmaf(-mu, scv, beta[lane]);
  float wv = Wout[lane];
  float bo = bout[0];
  for (int r = wid; r < n; r += nw) {
    float v = fmaxf(0.f, fmaf(y[(size_t)r * DH + lane], sc, sh)) * wv;
    #pragma unroll
    for (int off = 32; off; off >>= 1) v += __shfl_xor(v, off);
    if (lane == 0) out[r] = v + bo;
  }
}

extern "C" void kernel_launch(void* const* d_in, const int* in_sizes, int n_in,
                              void* d_out, int out_size, void* d_ws, size_t ws_size,
                              hipStream_t stream) {
  const float* x     = (const float*)d_in[0];
  const int*   ei    = (const int*)  d_in[1];
  const float* W0    = (const float*)d_in[2];
  const float* b0    = (const float*)d_in[3];
  const float* W1    = (const float*)d_in[4];
  const float* b1    = (const float*)d_in[5];
  const float* W2    = (const float*)d_in[6];
  const float* b2    = (const float*)d_in[7];
  const float* gamma = (const float*)d_in[8];
  const float* beta  = (const float*)d_in[9];
  const float* Wout  = (const float*)d_in[10];
  const float* bout  = (const float*)d_in[11];
  float* out = (float*)d_out;

  const int n = in_sizes[0] / 128;  // d_in = 128
  const int e = in_sizes[1] / 2;
  const int* src = ei;
  const int* dst = ei + e;
  const float inv_n = 1.0f / (float)n;

  const int nblk_scan = (n + 255) / 256;

  // Workspace layout (4-byte elements), 64-elem aligned blocks.
  auto a64 = [](size_t v) { return (v + 63) & ~(size_t)63; };
  char* ws = (char*)d_ws;
  size_t o_degi = 0;                          // int[n]    (zeroed)
  size_t o_S    = a64(o_degi + n);            // f32[3*128] (zeroed)
  size_t o_part = a64(o_S + 3 * 2 * DH);      // int[nblk_scan]
  size_t o_off  = a64(o_part + nblk_scan);    // int[n+1]
  size_t o_cur  = a64(o_off + n + 1);         // int[n]  (scan loc -> fill cursor)
  size_t o_csr  = a64(o_cur + n);             // int[e]
  size_t o_dinv = a64(o_csr + e);             // f32[n]
  size_t o_hn   = a64(o_dinv + n);            // f32[n*64]
  size_t o_y    = o_hn + (size_t)n * DH;      // f32[n*64]
  int*   degi  = (int*)  (ws + o_degi * 4);
  float* S     = (float*)(ws + o_S * 4);
  int*   part  = (int*)  (ws + o_part * 4);
  int*   off   = (int*)  (ws + o_off * 4);
  int*   cur   = (int*)  (ws + o_cur * 4);
  int*   csr   = (int*)  (ws + o_csr * 4);
  float* dinv  = (float*)(ws + o_dinv * 4);
  float* hn    = (float*)(ws + o_hn * 4);
  float* y     = (float*)(ws + o_y * 4);

  // Zero degi + BN-stat accumulators in one memset (they are adjacent).
  hipMemsetAsync(ws, 0, o_part * 4, stream);

  // CSR build (once; reused by all 3 layers).
  k_count<<<(e + 255) / 256, 256, 0, stream>>>(dst, degi, e);
  k_scan1<<<nblk_scan, 256, 0, stream>>>(degi, dinv, cur, part, n);
  k_scan2<<<nblk_scan, 256, 0, stream>>>(part, cur, off, n, e);
  k_fill<<<(e + 255) / 256, 256, 0, stream>>>(src, dst, cur, csr, e);

  const int gemm_blocks = (n + 15) / 16;  // 4 waves/block * 4 rows/wave

  // Layer 0
  k_gemm<128, false><<<gemm_blocks, 256, 0, stream>>>(x, W0, dinv, nullptr, nullptr,
                                                      nullptr, 0.f, hn, n);
  k_aggbn<<<2048, 256, 0, stream>>>(hn, off, csr, dinv, b0, y, S + 0 * 128, n);
  // Layer 1 (BN+ReLU of layer 0 fused into GEMM load; scale/shift inline from S)
  k_gemm<64, true><<<gemm_blocks, 256, 0, stream>>>(y, W1, dinv, S + 0 * 128,
                                                    gamma + 0 * DH, beta + 0 * DH,
                                                    inv_n, hn, n);
  k_aggbn<<<2048, 256, 0, stream>>>(hn, off, csr, dinv, b1, y, S + 1 * 128, n);
  // Layer 2
  k_gemm<64, true><<<gemm_blocks, 256, 0, stream>>>(y, W2, dinv, S + 1 * 128,
                                                    gamma + 1 * DH, beta + 1 * DH,
                                                    inv_n, hn, n);
  k_aggbn<<<2048, 256, 0, stream>>>(hn, off, csr, dinv, b2, y, S + 2 * 128, n);
  // Output projection (BN+ReLU of layer 2 fused)
  k_out<<<512, 256, 0, stream>>>(y, S + 2 * 128, gamma + 2 * DH, beta + 2 * DH,
                                 inv_n, Wout, bout, out, n);
}

// Round 8
// 483.147 us; speedup vs baseline: 1.0969x; 1.0969x over previous
//
#include <hip/hip_runtime.h>

#define DH 64
#define BN_EPS 1e-5f

typedef _Float16 f16;

__device__ __forceinline__ float lane_bcast(float v, int k) {
  return __int_as_float(__builtin_amdgcn_readlane(__float_as_int(v), k));
}

__global__ __launch_bounds__(256) void k_count(const int* __restrict__ dst,
                                               int* __restrict__ degi, int e) {
  int i = blockIdx.x * 256 + threadIdx.x;
  if (i < e) atomicAdd(&degi[dst[i]], 1);
}

// Per-block scan: local exclusive prefix -> loc (=cursor buf), block total -> partial.
__global__ __launch_bounds__(256) void k_scan1(const int* __restrict__ degi,
    float* __restrict__ dinv, int* __restrict__ loc, int* __restrict__ partial, int n)
{
  const int t = threadIdx.x;
  const int i = blockIdx.x * 256 + t;
  int v = (i < n) ? degi[i] : 0;
  if (i < n) dinv[i] = 1.0f / sqrtf((float)v + 1.0f);
  __shared__ int sc[256];
  sc[t] = v;
  __syncthreads();
  #pragma unroll
  for (int d = 1; d < 256; d <<= 1) {
    int u = (t >= d) ? sc[t - d] : 0;
    __syncthreads();
    sc[t] += u;
    __syncthreads();
  }
  if (i < n) loc[i] = sc[t] - v;              // local exclusive
  if (t == 255) partial[blockIdx.x] = sc[t];  // block total
}

__global__ __launch_bounds__(256) void k_scan2(const int* __restrict__ partial,
    int* __restrict__ loc_cursor, int* __restrict__ off, int n, int e)
{
  const int t = threadIdx.x;
  __shared__ int red[256];
  int s = 0;
  for (int i = t; i < (int)blockIdx.x; i += 256) s += partial[i];
  red[t] = s;
  __syncthreads();
  #pragma unroll
  for (int d = 128; d; d >>= 1) {
    if (t < d) red[t] += red[t + d];
    __syncthreads();
  }
  const int base = red[0];
  const int i = blockIdx.x * 256 + t;
  if (i < n) {
    int o = loc_cursor[i] + base;
    off[i] = o;
    loc_cursor[i] = o;  // becomes the fill cursor
  }
  if (i == n) off[n] = e;
}

__global__ __launch_bounds__(256) void k_fill(const int* __restrict__ src,
    const int* __restrict__ dst, int* __restrict__ cursor,
    int* __restrict__ csr, int e)
{
  int i = blockIdx.x * 256 + threadIdx.x;
  if (i < e) {
    int p = atomicAdd(&cursor[dst[i]], 1);
    csr[p] = src[i];
  }
}

// hn[r][c] = fp16((X@W)[r][c] * dinv[r]).  fp16 halves the aggbn gather
// row to one 128B cache line (the aggbn fabric-throughput wall is ~1.2TB/s
// on L2-miss fills, so bytes == time there).
// APPLY: X is previous layer's pre-BN y (f32); BN scale/shift inline from S.
template<int K, bool APPLY>
__global__ __launch_bounds__(256) void k_gemm(const float* __restrict__ X,
    const float* __restrict__ W, const float* __restrict__ dinv,
    const float* __restrict__ S, const float* __restrict__ gamma,
    const float* __restrict__ beta, float inv_n, f16* __restrict__ hn, int n)
{
  __shared__ float Wl[K * DH];
  for (int i = threadIdx.x; i < K * DH; i += 256) Wl[i] = W[i];
  __syncthreads();
  const int lane = threadIdx.x & 63;
  const int wid = blockIdx.x * 4 + (threadIdx.x >> 6);
  const int r0 = wid * 4;
  if (r0 >= n) return;
  float sc = 0.f, sh = 0.f;
  if (APPLY) {
    float mu = S[lane] * inv_n;
    float var = S[DH + lane] * inv_n - mu * mu;
    float scv = gamma[lane] / sqrtf(var + BN_EPS);
    sc = scv;
    sh = fmaf(-mu, scv, beta[lane]);
  }
  float xa[4], xb[4], acc[4];
  #pragma unroll
  for (int i = 0; i < 4; i++) {
    int r = r0 + i; if (r > n - 1) r = n - 1;
    const float* xr = X + (size_t)r * K;
    float v = xr[lane];
    if (APPLY) v = fmaxf(0.f, fmaf(v, sc, sh));
    xa[i] = v;
    if (K == 128) xb[i] = xr[DH + lane];
    acc[i] = 0.f;
  }
  #pragma unroll
  for (int k = 0; k < DH; k++) {
    float w = Wl[k * DH + lane];
    #pragma unroll
    for (int i = 0; i < 4; i++) acc[i] = fmaf(lane_bcast(xa[i], k), w, acc[i]);
  }
  if (K == 128) {
    #pragma unroll
    for (int k = 0; k < DH; k++) {
      float w = Wl[(DH + k) * DH + lane];
      #pragma unroll
      for (int i = 0; i < 4; i++) acc[i] = fmaf(lane_bcast(xb[i], k), w, acc[i]);
    }
  }
  #pragma unroll
  for (int i = 0; i < 4; i++) {
    if (r0 + i < n) hn[(size_t)(r0 + i) * DH + lane] = (f16)(acc[i] * dinv[r0 + i]);
  }
}

// Fused: agg = hn[d] + sum_{j in bucket(d)} hn[csr[j]] (fp16 rows, f32 accum);
// y = agg*dinv[d] + b (f32); accumulate per-column BN stats into S.
// R4 structure: 8 independent gather chains, low VGPR, grid 2048 (max waves).
__global__ __launch_bounds__(256) void k_aggbn(const f16* __restrict__ hn,
    const int* __restrict__ off, const int* __restrict__ csr,
    const float* __restrict__ dinv, const float* __restrict__ b,
    float* __restrict__ y, float* __restrict__ S, int n)
{
  const int lane = threadIdx.x & 63;
  const int w = threadIdx.x >> 6;
  const int wid = __builtin_amdgcn_readfirstlane(blockIdx.x * 4 + w);
  const int nw = gridDim.x * 4;
  float bias = b[lane];
  float s1 = 0.f, s2 = 0.f;
  for (int d = wid; d < n; d += nw) {
    const size_t base = (size_t)d * DH + lane;
    float a0 = (float)hn[base];  // self-loop term
    float a1 = 0.f, a2 = 0.f, a3 = 0.f, a4 = 0.f, a5 = 0.f, a6 = 0.f, a7 = 0.f;
    int j = off[d];
    const int end = off[d + 1];
    for (; j + 7 < end; j += 8) {
      int e0 = csr[j],     e1 = csr[j + 1], e2 = csr[j + 2], e3 = csr[j + 3];
      int e4 = csr[j + 4], e5 = csr[j + 5], e6 = csr[j + 6], e7 = csr[j + 7];
      float g0 = (float)hn[(size_t)e0 * DH + lane];
      float g1 = (float)hn[(size_t)e1 * DH + lane];
      float g2 = (float)hn[(size_t)e2 * DH + lane];
      float g3 = (float)hn[(size_t)e3 * DH + lane];
      float g4 = (float)hn[(size_t)e4 * DH + lane];
      float g5 = (float)hn[(size_t)e5 * DH + lane];
      float g6 = (float)hn[(size_t)e6 * DH + lane];
      float g7 = (float)hn[(size_t)e7 * DH + lane];
      a0 += g0; a1 += g1; a2 += g2; a3 += g3;
      a4 += g4; a5 += g5; a6 += g6; a7 += g7;
    }
    for (; j + 3 < end; j += 4) {
      int e0 = csr[j], e1 = csr[j + 1], e2 = csr[j + 2], e3 = csr[j + 3];
      a0 += (float)hn[(size_t)e0 * DH + lane];
      a1 += (float)hn[(size_t)e1 * DH + lane];
      a2 += (float)hn[(size_t)e2 * DH + lane];
      a3 += (float)hn[(size_t)e3 * DH + lane];
    }
    for (; j < end; j++) a0 += (float)hn[(size_t)csr[j] * DH + lane];
    float v = fmaf(((a0 + a1) + (a2 + a3)) + ((a4 + a5) + (a6 + a7)),
                   dinv[d], bias);
    y[base] = v;
    s1 += v;
    s2 = fmaf(v, v, s2);
  }
  __shared__ float L[8][DH];
  L[w][lane] = s1; L[4 + w][lane] = s2;
  __syncthreads();
  if (threadIdx.x < DH) {
    float t1 = L[0][lane] + L[1][lane] + L[2][lane] + L[3][lane];
    float t2 = L[4][lane] + L[5][lane] + L[6][lane] + L[7][lane];
    atomicAdd(&S[lane], t1);
    atomicAdd(&S[DH + lane], t2);
  }
}

// out[r] = sum_c relu(BN(y[r][c])) * Wout[c] + bout  (BN inline from S)
__global__ __launch_bounds__(256) void k_out(const float* __restrict__ y,
    const float* __restrict__ S, const float* __restrict__ gamma,
    const float* __restrict__ beta, float inv_n,
    const float* __restrict__ Wout, const float* __restrict__ bout,
    float* __restrict__ out, int n)
{
  const int lane = threadIdx.x & 63;
  const int wid = blockIdx.x * 4 + (threadIdx.x >> 6);
  const int nw = gridDim.x * 4;
  float mu = S[lane] * inv_n;
  float var = S[DH + lane] * inv_n - mu * mu;
  float scv = gamma[lane] / sqrtf(var + BN_EPS);
  float sc = scv;
  float sh = fmaf(-mu, scv, beta[lane]);
  float wv = Wout[lane];
  float bo = bout[0];
  for (int r = wid; r < n; r += nw) {
    float v = fmaxf(0.f, fmaf(y[(size_t)r * DH + lane], sc, sh)) * wv;
    #pragma unroll
    for (int off = 32; off; off >>= 1) v += __shfl_xor(v, off);
    if (lane == 0) out[r] = v + bo;
  }
}

extern "C" void kernel_launch(void* const* d_in, const int* in_sizes, int n_in,
                              void* d_out, int out_size, void* d_ws, size_t ws_size,
                              hipStream_t stream) {
  const float* x     = (const float*)d_in[0];
  const int*   ei    = (const int*)  d_in[1];
  const float* W0    = (const float*)d_in[2];
  const float* b0    = (const float*)d_in[3];
  const float* W1    = (const float*)d_in[4];
  const float* b1    = (const float*)d_in[5];
  const float* W2    = (const float*)d_in[6];
  const float* b2    = (const float*)d_in[7];
  const float* gamma = (const float*)d_in[8];
  const float* beta  = (const float*)d_in[9];
  const float* Wout  = (const float*)d_in[10];
  const float* bout  = (const float*)d_in[11];
  float* out = (float*)d_out;

  const int n = in_sizes[0] / 128;  // d_in = 128
  const int e = in_sizes[1] / 2;
  const int* src = ei;
  const int* dst = ei + e;
  const float inv_n = 1.0f / (float)n;

  const int nblk_scan = (n + 255) / 256;

  // Workspace layout (BYTE offsets, 256B-aligned blocks).
  auto aln = [](size_t v) { return (v + 255) & ~(size_t)255; };
  char* ws = (char*)d_ws;
  size_t o_degi = 0;                                  // int[n]     (zeroed)
  size_t o_S    = o_degi + (size_t)n * 4;             // f32[3*128] (zeroed, adjacent)
  size_t o_part = aln(o_S + 3 * 2 * DH * 4);          // int[nblk_scan]
  size_t o_off  = aln(o_part + (size_t)nblk_scan * 4);// int[n+1]
  size_t o_cur  = aln(o_off + ((size_t)n + 1) * 4);   // int[n]  (scan loc -> fill cursor)
  size_t o_csr  = aln(o_cur + (size_t)n * 4);         // int[e]
  size_t o_dinv = aln(o_csr + (size_t)e * 4);         // f32[n]
  size_t o_hn   = aln(o_dinv + (size_t)n * 4);        // f16[n*64]
  size_t o_y    = aln(o_hn + (size_t)n * DH * 2);     // f32[n*64]
  int*   degi  = (int*)  (ws + o_degi);
  float* S     = (float*)(ws + o_S);
  int*   part  = (int*)  (ws + o_part);
  int*   off   = (int*)  (ws + o_off);
  int*   cur   = (int*)  (ws + o_cur);
  int*   csr   = (int*)  (ws + o_csr);
  float* dinv  = (float*)(ws + o_dinv);
  f16*   hn    = (f16*)  (ws + o_hn);
  float* y     = (float*)(ws + o_y);

  // Zero degi + BN-stat accumulators in one memset (they are adjacent).
  hipMemsetAsync(ws, 0, o_part, stream);

  // CSR build (once; reused by all 3 layers).
  k_count<<<(e + 255) / 256, 256, 0, stream>>>(dst, degi, e);
  k_scan1<<<nblk_scan, 256, 0, stream>>>(degi, dinv, cur, part, n);
  k_scan2<<<nblk_scan, 256, 0, stream>>>(part, cur, off, n, e);
  k_fill<<<(e + 255) / 256, 256, 0, stream>>>(src, dst, cur, csr, e);

  const int gemm_blocks = (n + 15) / 16;  // 4 waves/block * 4 rows/wave

  // Layer 0
  k_gemm<128, false><<<gemm_blocks, 256, 0, stream>>>(x, W0, dinv, nullptr, nullptr,
                                                      nullptr, 0.f, hn, n);
  k_aggbn<<<2048, 256, 0, stream>>>(hn, off, csr, dinv, b0, y, S + 0 * 128, n);
  // Layer 1 (BN+ReLU of layer 0 fused into GEMM load; scale/shift inline from S)
  k_gemm<64, true><<<gemm_blocks, 256, 0, stream>>>(y, W1, dinv, S + 0 * 128,
                                                    gamma + 0 * DH, beta + 0 * DH,
                                                    inv_n, hn, n);
  k_aggbn<<<2048, 256, 0, stream>>>(hn, off, csr, dinv, b1, y, S + 1 * 128, n);
  // Layer 2
  k_gemm<64, true><<<gemm_blocks, 256, 0, stream>>>(y, W2, dinv, S + 1 * 128,
                                                    gamma + 1 * DH, beta + 1 * DH,
                                                    inv_n, hn, n);
  k_aggbn<<<2048, 256, 0, stream>>>(hn, off, csr, dinv, b2, y, S + 2 * 128, n);
  // Output projection (BN+ReLU of layer 2 fused)
  k_out<<<512, 256, 0, stream>>>(y, S + 2 * 128, gamma + 2 * DH, beta + 2 * DH,
                                 inv_n, Wout, bout, out, n);
}

// Round 10
// 430.724 us; speedup vs baseline: 1.2304x; 1.1217x over previous
//
#include <hip/hip_runtime.h>

#define DH 64
#define BN_EPS 1e-5f

typedef _Float16 f16;
typedef _Float16 f16x8 __attribute__((ext_vector_type(8)));
typedef float f32x4 __attribute__((ext_vector_type(4)));

__global__ __launch_bounds__(256) void k_count(const int* __restrict__ dst,
                                               int* __restrict__ degi, int e) {
  int i = blockIdx.x * 256 + threadIdx.x;
  if (i < e) atomicAdd(&degi[dst[i]], 1);
}

// Per-block scan: local exclusive prefix -> loc (=cursor buf), block total -> partial.
__global__ __launch_bounds__(256) void k_scan1(const int* __restrict__ degi,
    float* __restrict__ dinv, int* __restrict__ loc, int* __restrict__ partial, int n)
{
  const int t = threadIdx.x;
  const int i = blockIdx.x * 256 + t;
  int v = (i < n) ? degi[i] : 0;
  if (i < n) dinv[i] = 1.0f / sqrtf((float)v + 1.0f);
  __shared__ int sc[256];
  sc[t] = v;
  __syncthreads();
  #pragma unroll
  for (int d = 1; d < 256; d <<= 1) {
    int u = (t >= d) ? sc[t - d] : 0;
    __syncthreads();
    sc[t] += u;
    __syncthreads();
  }
  if (i < n) loc[i] = sc[t] - v;              // local exclusive
  if (t == 255) partial[blockIdx.x] = sc[t];  // block total
}

__global__ __launch_bounds__(256) void k_scan2(const int* __restrict__ partial,
    int* __restrict__ loc_cursor, int* __restrict__ off, int n, int e)
{
  const int t = threadIdx.x;
  __shared__ int red[256];
  int s = 0;
  for (int i = t; i < (int)blockIdx.x; i += 256) s += partial[i];
  red[t] = s;
  __syncthreads();
  #pragma unroll
  for (int d = 128; d; d >>= 1) {
    if (t < d) red[t] += red[t + d];
    __syncthreads();
  }
  const int base = red[0];
  const int i = blockIdx.x * 256 + t;
  if (i < n) {
    int o = loc_cursor[i] + base;
    off[i] = o;
    loc_cursor[i] = o;  // becomes the fill cursor
  }
  if (i == n) off[n] = e;
}

__global__ __launch_bounds__(256) void k_fill(const int* __restrict__ src,
    const int* __restrict__ dst, int* __restrict__ cursor,
    int* __restrict__ csr, int e)
{
  int i = blockIdx.x * 256 + threadIdx.x;
  if (i < e) {
    int p = atomicAdd(&cursor[dst[i]], 1);
    csr[p] = src[i];
  }
}

// All three weights: Wt[c][k] = fp16(W[k][c]) (transposed so MFMA B-fragments
// are 16B-contiguous). One launch for W0(128x64), W1(64x64), W2(64x64).
__global__ __launch_bounds__(256) void k_wprep(const float* __restrict__ W0,
    const float* __restrict__ W1, const float* __restrict__ W2,
    f16* __restrict__ wt0, f16* __restrict__ wt1, f16* __restrict__ wt2)
{
  int idx = blockIdx.x * 256 + threadIdx.x;
  if (idx < 128 * DH) {
    int k = idx >> 6, c = idx & 63;
    wt0[(size_t)c * 128 + k] = (f16)W0[idx];
  }
  if (idx < 64 * DH) {
    int k = idx >> 6, c = idx & 63;
    wt1[(size_t)c * 64 + k] = (f16)W1[idx];
    wt2[(size_t)c * 64 + k] = (f16)W2[idx];
  }
}

// ss[c] = gamma/sqrt(var+eps); ss[DH+c] = beta - mu*scale   (from BN stats S)
__global__ __launch_bounds__(64) void k_scaleshift(const float* __restrict__ S,
    const float* __restrict__ gamma, const float* __restrict__ beta,
    float* __restrict__ ss, float inv_n)
{
  int c = threadIdx.x;
  float mu = S[c] * inv_n;
  float var = S[DH + c] * inv_n - mu * mu;
  float scv = gamma[c] / sqrtf(var + BN_EPS);
  ss[c] = scv;
  ss[DH + c] = fmaf(-mu, scv, beta[c]);
}

// MFMA GEMM: hn[r][c] = fp16( (fp16(X') @ Wt^T)[r][c] * dinv[r] ),
// X' = APPLY ? relu(X*sc+sh) : X.  One wave = 16 rows x 64 cols via 4
// column tiles of 16x16x32_f16.  Fragment layout (guide-verified lineage):
//   A: row = lane&15,  k = (lane>>4)*8 + j  (8 consecutive k)
//   B: col = lane&15,  k = (lane>>4)*8 + j  (from Wt[c][k], contiguous 16B)
//   C: col = lane&15, row = (lane>>4)*4 + reg
template<int K, bool APPLY>
__global__ __launch_bounds__(256) void k_mfma(const float* __restrict__ X,
    const f16* __restrict__ Wt, const float* __restrict__ dinv,
    const float* __restrict__ ss, f16* __restrict__ hn, int n)
{
  const int lane = threadIdx.x & 63;
  const int wv = threadIdx.x >> 6;
  const int row0 = (blockIdx.x * 4 + wv) * 16;
  if (row0 >= n) return;
  const int r = lane & 15;
  const int g = lane >> 4;
  const int koff = g * 8;
  constexpr int NS = K / 32;

  f16x8 bfrag[4][NS];
  #pragma unroll
  for (int t = 0; t < 4; t++)
    #pragma unroll
    for (int s = 0; s < NS; s++)
      bfrag[t][s] = *(const f16x8*)(Wt + (size_t)(t * 16 + r) * K + s * 32 + koff);

  int row = row0 + r;
  if (row > n - 1) row = n - 1;
  f16x8 afrag[NS];
  #pragma unroll
  for (int s = 0; s < NS; s++) {
    const float* xp = X + (size_t)row * K + s * 32 + koff;
    f16x8 a;
    #pragma unroll
    for (int j = 0; j < 8; j++) {
      float v = xp[j];
      if (APPLY) {
        int c = s * 32 + koff + j;
        v = fmaxf(0.f, fmaf(v, ss[c], ss[DH + c]));
      }
      a[j] = (f16)v;
    }
    afrag[s] = a;
  }

  f32x4 acc0 = {0.f, 0.f, 0.f, 0.f};
  f32x4 acc1 = acc0, acc2 = acc0, acc3 = acc0;
  #pragma unroll
  for (int s = 0; s < NS; s++) {
    acc0 = __builtin_amdgcn_mfma_f32_16x16x32_f16(afrag[s], bfrag[0][s], acc0, 0, 0, 0);
    acc1 = __builtin_amdgcn_mfma_f32_16x16x32_f16(afrag[s], bfrag[1][s], acc1, 0, 0, 0);
    acc2 = __builtin_amdgcn_mfma_f32_16x16x32_f16(afrag[s], bfrag[2][s], acc2, 0, 0, 0);
    acc3 = __builtin_amdgcn_mfma_f32_16x16x32_f16(afrag[s], bfrag[3][s], acc3, 0, 0, 0);
  }

  #pragma unroll
  for (int reg = 0; reg < 4; reg++) {
    int orow = row0 + g * 4 + reg;
    if (orow < n) {
      float di = dinv[orow];
      f16* hp = hn + (size_t)orow * DH + r;
      hp[0]  = (f16)(acc0[reg] * di);
      hp[16] = (f16)(acc1[reg] * di);
      hp[32] = (f16)(acc2[reg] * di);
      hp[48] = (f16)(acc3[reg] * di);
    }
  }
}

// Fused: agg = hn[d] + sum_{j in bucket(d)} hn[csr[j]] (fp16 rows, f32 accum);
// y = agg*dinv[d] + b (f32); accumulate per-column BN stats into S.
__global__ __launch_bounds__(256) void k_aggbn(const f16* __restrict__ hn,
    const int* __restrict__ off, const int* __restrict__ csr,
    const float* __restrict__ dinv, const float* __restrict__ b,
    float* __restrict__ y, float* __restrict__ S, int n)
{
  const int lane = threadIdx.x & 63;
  const int w = threadIdx.x >> 6;
  const int wid = __builtin_amdgcn_readfirstlane(blockIdx.x * 4 + w);
  const int nw = gridDim.x * 4;
  float bias = b[lane];
  float s1 = 0.f, s2 = 0.f;
  for (int d = wid; d < n; d += nw) {
    const size_t base = (size_t)d * DH + lane;
    float a0 = (float)hn[base];  // self-loop term
    float a1 = 0.f, a2 = 0.f, a3 = 0.f, a4 = 0.f, a5 = 0.f, a6 = 0.f, a7 = 0.f;
    int j = off[d];
    const int end = off[d + 1];
    for (; j + 7 < end; j += 8) {
      int e0 = csr[j],     e1 = csr[j + 1], e2 = csr[j + 2], e3 = csr[j + 3];
      int e4 = csr[j + 4], e5 = csr[j + 5], e6 = csr[j + 6], e7 = csr[j + 7];
      float g0 = (float)hn[(size_t)e0 * DH + lane];
      float g1 = (float)hn[(size_t)e1 * DH + lane];
      float g2 = (float)hn[(size_t)e2 * DH + lane];
      float g3 = (float)hn[(size_t)e3 * DH + lane];
      float g4 = (float)hn[(size_t)e4 * DH + lane];
      float g5 = (float)hn[(size_t)e5 * DH + lane];
      float g6 = (float)hn[(size_t)e6 * DH + lane];
      float g7 = (float)hn[(size_t)e7 * DH + lane];
      a0 += g0; a1 += g1; a2 += g2; a3 += g3;
      a4 += g4; a5 += g5; a6 += g6; a7 += g7;
    }
    for (; j + 3 < end; j += 4) {
      int e0 = csr[j], e1 = csr[j + 1], e2 = csr[j + 2], e3 = csr[j + 3];
      a0 += (float)hn[(size_t)e0 * DH + lane];
      a1 += (float)hn[(size_t)e1 * DH + lane];
      a2 += (float)hn[(size_t)e2 * DH + lane];
      a3 += (float)hn[(size_t)e3 * DH + lane];
    }
    for (; j < end; j++) a0 += (float)hn[(size_t)csr[j] * DH + lane];
    float v = fmaf(((a0 + a1) + (a2 + a3)) + ((a4 + a5) + (a6 + a7)),
                   dinv[d], bias);
    y[base] = v;
    s1 += v;
    s2 = fmaf(v, v, s2);
  }
  __shared__ float L[8][DH];
  L[w][lane] = s1; L[4 + w][lane] = s2;
  __syncthreads();
  if (threadIdx.x < DH) {
    float t1 = L[0][lane] + L[1][lane] + L[2][lane] + L[3][lane];
    float t2 = L[4][lane] + L[5][lane] + L[6][lane] + L[7][lane];
    atomicAdd(&S[lane], t1);
    atomicAdd(&S[DH + lane], t2);
  }
}

// out[r] = sum_c relu(y[r][c]*sc+sh) * Wout[c] + bout
__global__ __launch_bounds__(256) void k_out(const float* __restrict__ y,
    const float* __restrict__ ss, const float* __restrict__ Wout,
    const float* __restrict__ bout, float* __restrict__ out, int n)
{
  const int lane = threadIdx.x & 63;
  const int wid = blockIdx.x * 4 + (threadIdx.x >> 6);
  const int nw = gridDim.x * 4;
  float wv = Wout[lane];
  float sc = ss[lane], sh = ss[DH + lane];
  float bo = bout[0];
  for (int r = wid; r < n; r += nw) {
    float v = fmaxf(0.f, fmaf(y[(size_t)r * DH + lane], sc, sh)) * wv;
    #pragma unroll
    for (int off = 32; off; off >>= 1) v += __shfl_xor(v, off);
    if (lane == 0) out[r] = v + bo;
  }
}

extern "C" void kernel_launch(void* const* d_in, const int* in_sizes, int n_in,
                              void* d_out, int out_size, void* d_ws, size_t ws_size,
                              hipStream_t stream) {
  const float* x     = (const float*)d_in[0];
  const int*   ei    = (const int*)  d_in[1];
  const float* W0    = (const float*)d_in[2];
  const float* b0    = (const float*)d_in[3];
  const float* W1    = (const float*)d_in[4];
  const float* b1    = (const float*)d_in[5];
  const float* W2    = (const float*)d_in[6];
  const float* b2    = (const float*)d_in[7];
  const float* gamma = (const float*)d_in[8];
  const float* beta  = (const float*)d_in[9];
  const float* Wout  = (const float*)d_in[10];
  const float* bout  = (const float*)d_in[11];
  float* out = (float*)d_out;

  const int n = in_sizes[0] / 128;  // d_in = 128
  const int e = in_sizes[1] / 2;
  const int* src = ei;
  const int* dst = ei + e;
  const float inv_n = 1.0f / (float)n;

  const int nblk_scan = (n + 255) / 256;

  // Workspace layout (BYTE offsets, 256B-aligned blocks).
  auto aln = [](size_t v) { return (v + 255) & ~(size_t)255; };
  char* ws = (char*)d_ws;
  size_t o_degi = 0;                                   // int[n]     (zeroed)
  size_t o_S    = o_degi + (size_t)n * 4;              // f32[3*128] (zeroed, adjacent)
  size_t o_part = aln(o_S + 3 * 2 * DH * 4);           // int[nblk_scan]
  size_t o_off  = aln(o_part + (size_t)nblk_scan * 4); // int[n+1]
  size_t o_cur  = aln(o_off + ((size_t)n + 1) * 4);    // int[n]
  size_t o_csr  = aln(o_cur + (size_t)n * 4);          // int[e]
  size_t o_dinv = aln(o_csr + (size_t)e * 4);          // f32[n]
  size_t o_hn   = aln(o_dinv + (size_t)n * 4);         // f16[n*64]
  size_t o_y    = aln(o_hn + (size_t)n * DH * 2);      // f32[n*64]
  size_t o_wt0  = aln(o_y + (size_t)n * DH * 4);       // f16[128*64]
  size_t o_wt1  = aln(o_wt0 + 128 * DH * 2);           // f16[64*64]
  size_t o_wt2  = aln(o_wt1 + 64 * DH * 2);            // f16[64*64]
  size_t o_ss   = aln(o_wt2 + 64 * DH * 2);            // f32[3*128]
  int*   degi  = (int*)  (ws + o_degi);
  float* S     = (float*)(ws + o_S);
  int*   part  = (int*)  (ws + o_part);
  int*   off   = (int*)  (ws + o_off);
  int*   cur   = (int*)  (ws + o_cur);
  int*   csr   = (int*)  (ws + o_csr);
  float* dinv  = (float*)(ws + o_dinv);
  f16*   hn    = (f16*)  (ws + o_hn);
  float* y     = (float*)(ws + o_y);
  f16*   wt0   = (f16*)  (ws + o_wt0);
  f16*   wt1   = (f16*)  (ws + o_wt1);
  f16*   wt2   = (f16*)  (ws + o_wt2);
  float* ss    = (float*)(ws + o_ss);

  // Zero degi + BN-stat accumulators in one memset (adjacent).
  hipMemsetAsync(ws, 0, o_part, stream);

  // Weight transpose+fp16 (tiny, once, single launch).
  k_wprep<<<(128 * DH + 255) / 256, 256, 0, stream>>>(W0, W1, W2, wt0, wt1, wt2);

  // CSR build (once; reused by all 3 layers).
  k_count<<<(e + 255) / 256, 256, 0, stream>>>(dst, degi, e);
  k_scan1<<<nblk_scan, 256, 0, stream>>>(degi, dinv, cur, part, n);
  k_scan2<<<nblk_scan, 256, 0, stream>>>(part, cur, off, n, e);
  k_fill<<<(e + 255) / 256, 256, 0, stream>>>(src, dst, cur, csr, e);

  const int mfma_blocks = (n + 63) / 64;  // 4 waves/block * 16 rows/wave

  // Layer 0
  k_mfma<128, false><<<mfma_blocks, 256, 0, stream>>>(x, wt0, dinv, nullptr, hn, n);
  k_aggbn<<<2048, 256, 0, stream>>>(hn, off, csr, dinv, b0, y, S + 0 * 128, n);
  k_scaleshift<<<1, 64, 0, stream>>>(S + 0 * 128, gamma + 0 * DH, beta + 0 * DH,
                                     ss + 0 * 128, inv_n);
  // Layer 1 (BN+ReLU of layer 0 fused into MFMA A-load)
  k_mfma<64, true><<<mfma_blocks, 256, 0, stream>>>(y, wt1, dinv, ss + 0 * 128, hn, n);
  k_aggbn<<<2048, 256, 0, stream>>>(hn, off, csr, dinv, b1, y, S + 1 * 128, n);
  k_scaleshift<<<1, 64, 0, stream>>>(S + 1 * 128, gamma + 1 * DH, beta + 1 * DH,
                                     ss + 1 * 128, inv_n);
  // Layer 2
  k_mfma<64, true><<<mfma_blocks, 256, 0, stream>>>(y, wt2, dinv, ss + 1 * 128, hn, n);
  k_aggbn<<<2048, 256, 0, stream>>>(hn, off, csr, dinv, b2, y, S + 2 * 128, n);
  k_scaleshift<<<1, 64, 0, stream>>>(S + 2 * 128, gamma + 2 * DH, beta + 2 * DH,
                                     ss + 2 * 128, inv_n);
  // Output projection (BN+ReLU of layer 2 fused)
  k_out<<<512, 256, 0, stream>>>(y, ss + 2 * 128, Wout, bout, out, n);
}